// Round 3
// baseline (245.801 us; speedup 1.0000x reference)
//
#include <hip/hip_runtime.h>
#include <hip/hip_bf16.h>

#define NN 100000   // nodes
#define NE 1600000  // edges
#define NG 1000     // graphs
#define NBK 196     // dst buckets of 512 nodes (196*512 >= NN)
#define BSH 9       // bucket shift
#define SLOT 10240  // tmp slack region per bucket (mean 8192 + padding)
#define SLOTC 12288 // csr slack region per bucket (mean 8192 + 8-align pad ~3.5/node)

typedef short short8 __attribute__((ext_vector_type(8)));
typedef float f32x4 __attribute__((ext_vector_type(4)));
typedef float f32x2 __attribute__((ext_vector_type(2)));

static inline int cdiv(int a, int b) { return (a + b - 1) / b; }

// f32 -> bf16 (RNE) and helpers
__device__ __forceinline__ unsigned short f2b(float f) {
    unsigned int u = __float_as_uint(f);
    u += 0x7fff + ((u >> 16) & 1);
    return (unsigned short)(u >> 16);
}
__device__ __forceinline__ unsigned int pack2(float lo, float hi) {
    return (unsigned int)f2b(lo) | ((unsigned int)f2b(hi) << 16);
}

// fp8 e4m3 (OCP) hardware converts; word select must be an immediate constant
template <int W>
__device__ __forceinline__ f32x2 f8_2f(unsigned int v) {
    return __builtin_amdgcn_cvt_pk_f32_fp8((int)v, W);
}
__device__ __forceinline__ unsigned int f2f8_lo(float a, float b, unsigned int old) {
    return (unsigned int)__builtin_amdgcn_cvt_pk_fp8_f32(a, b, (int)old, false);
}
__device__ __forceinline__ unsigned int f2f8_hi(float a, float b, unsigned int old) {
    return (unsigned int)__builtin_amdgcn_cvt_pk_fp8_f32(a, b, (int)old, true);
}
__device__ __forceinline__ unsigned char f2f8s(float a) {
    return (unsigned char)(__builtin_amdgcn_cvt_pk_fp8_f32(a, a, 0, false) & 0xFF);
}

// ------------------------------------------------- prep
// Permuted byte order for fp8 rows: byte q holds col c(q) = (q&7)*16 + (q>>3).
// Wt1: bf16 [n][k] for layer-1 bf16 MFMA.
// Wt2p: fp8 [n][q] with k-rows permuted by the SAME c(q) as A1's byte order —
// joint k-permutation of A and B leaves the dot product invariant.
// Block 128 also zeroes row NN of Hs8 (dummy target) and the degree bins.
// Blocks >= 129: scan sorted batch[] for graph start offsets.
__global__ __launch_bounds__(256) void k_prep(const float* __restrict__ W1,
                                              const float* __restrict__ W2,
                                              const float* __restrict__ b1,
                                              const float* __restrict__ b2,
                                              unsigned short* __restrict__ Wt1,
                                              unsigned char* __restrict__ Wt2p,
                                              float* __restrict__ b1p,
                                              float* __restrict__ b2p,
                                              int* __restrict__ gcur,
                                              const int* __restrict__ batch,
                                              int* __restrict__ gstart,
                                              unsigned char* __restrict__ Hs8,
                                              int* __restrict__ dbins) {
    int b = blockIdx.x, t = threadIdx.x;
    if (b < 128) {
        if (t < 128) {
            Wt1[b * 128 + t] = f2b(W1[t * 128 + b]);
        } else {
            int q = t - 128;
            int c = (q & 7) * 16 + (q >> 3);
            Wt2p[b * 128 + q] = f2f8s(W2[c * 128 + b]);
        }
    } else if (b == 128) {
        if (t < NBK) gcur[t] = t * SLOT;
        if (t < 128) {
            int c = (t & 7) * 16 + (t >> 3);  // col held at permuted position t
            b1p[t] = b1[c];
            b2p[t] = b2[c];
        }
        if (t >= 128 && t < 136) {
            uint4 z; z.x = 0u; z.y = 0u; z.z = 0u; z.w = 0u;
            ((uint4*)(Hs8 + (size_t)NN * 128))[t - 128] = z;  // zero dummy row
        }
        if (t >= 192) dbins[t - 192] = 0;  // 64 degree bins
    } else {
        // graph boundary scan: n in [0, NN]; virtual batch[NN] = NG
        int n = (b - 129) * 256 + t;
        if (n <= NN) {
            int cur = (n == NN) ? NG : batch[n];
            int prev = (n == 0) ? -1 : batch[n - 1];
            for (int g = prev + 1; g <= cur; g++) gstart[g] = n;
        }
    }
}

// -------------------------------------------------------- two-phase binning
// LDS counting-sort (R17-verified): entries sorted into bucket order in LDS,
// then written out linearly (coalesced).
__global__ __launch_bounds__(256) void k_bin2(const int* __restrict__ row,
                                              const int* __restrict__ col,
                                              int* __restrict__ gcur,
                                              unsigned int* __restrict__ tmp) {
    __shared__ unsigned int ent[4000];
    __shared__ unsigned int srt[4000];
    __shared__ unsigned char bkt[4000];
    __shared__ unsigned char bky[4000];
    __shared__ int cnt[NBK];
    __shared__ int gbase[NBK];
    __shared__ int lbase[NBK];
    __shared__ int sh[256];
    int t = threadIdx.x;
    if (t < NBK) cnt[t] = 0;
    __syncthreads();
    const int q0 = blockIdx.x * 1000;  // int4 index base (4000 edges)
    const int4* col4 = (const int4*)col;
    const int4* row4 = (const int4*)row;
#pragma unroll
    for (int it = 0; it < 4; it++) {
        int idx = it * 256 + t;
        if (idx < 1000) {
            int4 c = col4[q0 + idx];
            int4 r = row4[q0 + idx];
            int d, b;
            d = c.x; b = d >> BSH; atomicAdd(&cnt[b], 1);
            ent[idx * 4 + 0] = ((unsigned int)(d & 511) << 17) | (unsigned int)r.x;
            bkt[idx * 4 + 0] = (unsigned char)b;
            d = c.y; b = d >> BSH; atomicAdd(&cnt[b], 1);
            ent[idx * 4 + 1] = ((unsigned int)(d & 511) << 17) | (unsigned int)r.y;
            bkt[idx * 4 + 1] = (unsigned char)b;
            d = c.z; b = d >> BSH; atomicAdd(&cnt[b], 1);
            ent[idx * 4 + 2] = ((unsigned int)(d & 511) << 17) | (unsigned int)r.z;
            bkt[idx * 4 + 2] = (unsigned char)b;
            d = c.w; b = d >> BSH; atomicAdd(&cnt[b], 1);
            ent[idx * 4 + 3] = ((unsigned int)(d & 511) << 17) | (unsigned int)r.w;
            bkt[idx * 4 + 3] = (unsigned char)b;
        }
    }
    __syncthreads();
    int v = (t < NBK) ? cnt[t] : 0;
    sh[t] = v;
    __syncthreads();
    for (int d = 1; d < 256; d <<= 1) {
        int u = (t >= d) ? sh[t - d] : 0;
        __syncthreads();
        sh[t] += u;
        __syncthreads();
    }
    if (t < NBK) {
        lbase[t] = sh[t] - v;
        gbase[t] = atomicAdd(&gcur[t], v);
        cnt[t] = sh[t] - v;  // becomes local cursor
    }
    __syncthreads();
#pragma unroll
    for (int it = 0; it < 16; it++) {
        int i = it * 256 + t;
        if (i < 4000) {
            int b = bkt[i];
            int p = atomicAdd(&cnt[b], 1);
            srt[p] = ent[i];
            bky[p] = (unsigned char)b;
        }
    }
    __syncthreads();
#pragma unroll
    for (int it = 0; it < 16; it++) {
        int i = it * 256 + t;
        if (i < 4000) {
            int b = bky[i];
            tmp[gbase[b] + (i - lbase[b])] = srt[i];
        }
    }
}

// -------------------------------------------------------- per-bucket CSR
// Segments padded to 8-entry alignment; pad entries filled with dummy index NN
// (points at the zeroed row of Hs8) so k_agg can gather unconditionally.
// meta[node] = csr_offset | (padded_degree << 22).
// Entries stashed in LDS during the count pass (no tmp re-read).
// Also accumulates the global degree-bin histogram for the degree sort
// (bin = 63 - min(degp/8, 63): descending so heavy nodes schedule first).
__global__ __launch_bounds__(1024) void k_bucket(const unsigned int* __restrict__ tmp,
                                                 const int* __restrict__ gcur,
                                                 unsigned int* __restrict__ meta,
                                                 float* __restrict__ dinv,
                                                 int* __restrict__ csr_src,
                                                 int* __restrict__ dbins) {
    __shared__ unsigned int sent[SLOT];  // 40 KB entry stash
    __shared__ int cnt[512];
    __shared__ int loff[512];
    __shared__ int send[512];
    __shared__ int sh[256];
    __shared__ int lbin[64];
    int b = blockIdx.x, t = threadIdx.x;
    int j0 = b << BSH;
    int nd = min(512, NN - j0);
    int rb = b * SLOT;     // tmp base
    int rbc = b * SLOTC;   // csr base
    int m = gcur[b] - rb;
    if (t < 512) cnt[t] = 0;
    if (t < 64) lbin[t] = 0;
    __syncthreads();
    for (int i = t; i < m; i += 1024) {
        unsigned int e = tmp[rb + i];
        sent[i] = e;
        atomicAdd(&cnt[e >> 17], 1);
    }
    __syncthreads();
    int r0 = 0, r1 = 0, p0 = 0, ts = 0;
    if (t < 256) {
        r0 = cnt[2 * t]; r1 = cnt[2 * t + 1];
        p0 = (r0 + 7) & ~7;
        int p1 = (r1 + 7) & ~7;  // pad to 8-entry alignment
        ts = p0 + p1;
        sh[t] = ts;
    }
    __syncthreads();
    for (int d = 1; d < 256; d <<= 1) {
        int u = (t >= d && t < 256) ? sh[t - d] : 0;
        __syncthreads();
        if (t < 256) sh[t] += u;
        __syncthreads();
    }
    if (t < 256) {
        int ex = sh[t] - ts;
        loff[2 * t] = ex;
        loff[2 * t + 1] = ex + p0;
    }
    __syncthreads();
    for (int j = t; j < nd; j += 1024) {
        int o = rbc + loff[j];
        int dg = cnt[j];
        int dgp = (dg + 7) & ~7;
        meta[j0 + j] = (unsigned int)o | ((unsigned int)dgp << 22);
        send[j] = o + dgp;
        dinv[j0 + j] = rsqrtf((float)(dg + 1));  // +1 self-loop
        atomicAdd(&lbin[63 - min(dgp >> 3, 63)], 1);
        cnt[j] = o;  // becomes cursor
    }
    __syncthreads();
    for (int i = t; i < m; i += 1024) {
        unsigned int e = sent[i];
        int d = e >> 17;
        int s = (int)(e & 0x1FFFFu);
        int p = atomicAdd(&cnt[d], 1);
        csr_src[p] = s;
    }
    __syncthreads();
    for (int j = t; j < nd; j += 1024) {
        int pe = send[j];
        for (int p = cnt[j]; p < pe; p++) csr_src[p] = NN;  // dummy (zero row)
    }
    if (t < 64 && lbin[t]) atomicAdd(&dbins[t], lbin[t]);
}

// -------------------------------------------------------- degree-sort scan
__global__ void k_scan(const int* __restrict__ dbins, int* __restrict__ gbincur) {
    if (threadIdx.x == 0) {
        int s = 0;
        for (int i = 0; i < 64; i++) { gbincur[i] = s; s += dbins[i]; }
    }
}

// -------------------------------------------------------- degree-sort scatter
// perm = node ids ordered by descending padded degree (bin-granular).
__global__ __launch_bounds__(256) void k_scatter(const unsigned int* __restrict__ meta,
                                                 int* __restrict__ gbincur,
                                                 int* __restrict__ perm) {
    __shared__ int lcnt[64];
    __shared__ int lbase[64];
    int t = threadIdx.x;
    int node = blockIdx.x * 256 + t;
    if (t < 64) lcnt[t] = 0;
    __syncthreads();
    int bin = 0, rank = 0;
    bool ok = node < NN;
    if (ok) {
        int dgp = (int)(meta[node] >> 22);
        bin = 63 - min(dgp >> 3, 63);
        rank = atomicAdd(&lcnt[bin], 1);
    }
    __syncthreads();
    if (t < 64 && lcnt[t] > 0) lbase[t] = atomicAdd(&gbincur[t], lcnt[t]);
    __syncthreads();
    if (ok) perm[lbase[bin] + rank] = node;
}

// ---------------------------------------------------------------- GEMM layer 1
// Hs8[r] = fp8( dinv[r] * (bf16(x) @ Wt1^T) row r ), PERMUTED bytes (q=n16*8+ct).
__global__ __launch_bounds__(256) void k_gemm1(const float* __restrict__ X,
                                               const unsigned short* __restrict__ Wt,
                                               const float* __restrict__ dinv,
                                               unsigned char* __restrict__ Hs8) {
    __shared__ __align__(16) unsigned short Ws[128 * 128];  // 32 KB
    int t = threadIdx.x;
#pragma unroll
    for (int i = 0; i < 8; i++) {
        int id = t + i * 256;
        int n = id >> 4, c = id & 15;
        *(short8*)((char*)Ws + n * 256 + ((c ^ (n & 15)) << 4)) =
            *(const short8*)(Wt + n * 128 + c * 8);
    }
    __syncthreads();

    int lane = t & 63, wid = t >> 6;
    int n16 = lane & 15, quad = lane >> 4;
    int row_base = blockIdx.x * 128 + wid * 32;

    short8 a[2][4];
#pragma unroll
    for (int rt = 0; rt < 2; rt++) {
        int r = row_base + rt * 16 + n16;
        if (r > NN - 1) r = NN - 1;
        const float* ap = X + (size_t)r * 128 + quad * 8;
#pragma unroll
        for (int ks = 0; ks < 4; ks++) {
            float4 v0 = *(const float4*)(ap + ks * 32);
            float4 v1 = *(const float4*)(ap + ks * 32 + 4);
            uint4 up;
            up.x = pack2(v0.x, v0.y); up.y = pack2(v0.z, v0.w);
            up.z = pack2(v1.x, v1.y); up.w = pack2(v1.z, v1.w);
            a[rt][ks] = *(short8*)&up;
        }
    }

    f32x4 acc[2][8];
#pragma unroll
    for (int rt = 0; rt < 2; rt++)
#pragma unroll
        for (int ct = 0; ct < 8; ct++)
            acc[rt][ct] = (f32x4){0.f, 0.f, 0.f, 0.f};

#pragma unroll
    for (int ks = 0; ks < 4; ks++) {
#pragma unroll
        for (int ct = 0; ct < 8; ct++) {
            short8 b = *(const short8*)((const char*)Ws +
                        (ct * 16 + n16) * 256 + ((((ks << 2) + quad) ^ n16) << 4));
            acc[0][ct] = __builtin_amdgcn_mfma_f32_16x16x32_bf16(a[0][ks], b, acc[0][ct], 0, 0, 0);
            acc[1][ct] = __builtin_amdgcn_mfma_f32_16x16x32_bf16(a[1][ks], b, acc[1][ct], 0, 0, 0);
        }
    }

#pragma unroll
    for (int rt = 0; rt < 2; rt++) {
#pragma unroll
        for (int reg = 0; reg < 4; reg++) {
            int row = row_base + rt * 16 + quad * 4 + reg;
            if (row < NN) {
                float di = dinv[row];
                unsigned int u0 = 0, u1 = 0;
                u0 = f2f8_lo(acc[rt][0][reg] * di, acc[rt][1][reg] * di, u0);
                u0 = f2f8_hi(acc[rt][2][reg] * di, acc[rt][3][reg] * di, u0);
                u1 = f2f8_lo(acc[rt][4][reg] * di, acc[rt][5][reg] * di, u1);
                u1 = f2f8_hi(acc[rt][6][reg] * di, acc[rt][7][reg] * di, u1);
                uint2 o; o.x = u0; o.y = u1;
                ((uint2*)(Hs8 + (size_t)row * 128))[n16] = o;
            }
        }
    }
}

// ---------------------------------------------------------------- GEMM layer 2
// fp8 x fp8 MFMA. A = A1 (fp8, permuted byte order); B = Wt2p (fp8, k-rows
// permuted by the same c(q)) -> joint k-permutation cancels in the dot product.
// LDS: 16 KB, XOR-8B-chunk swizzle (16 distinct banks per quad on b64 reads).
__global__ __launch_bounds__(256) void k_gemm2(const unsigned char* __restrict__ A8,
                                               const unsigned char* __restrict__ Wt2p,
                                               const float* __restrict__ dinv,
                                               unsigned char* __restrict__ Hs8) {
    __shared__ __align__(16) unsigned char Ws[128 * 128];  // 16 KB
    int t = threadIdx.x;
#pragma unroll
    for (int i = 0; i < 8; i++) {
        int id = t + i * 256;          // 2048 8-byte chunks
        int n = id >> 4, c = id & 15;
        *(uint2*)(Ws + n * 128 + ((c ^ (n & 15)) << 3)) =
            *(const uint2*)(Wt2p + n * 128 + c * 8);
    }
    __syncthreads();

    int lane = t & 63, wid = t >> 6;
    int n16 = lane & 15, quad = lane >> 4;
    int row_base = blockIdx.x * 128 + wid * 32;

    uint2 a[2][4];
#pragma unroll
    for (int rt = 0; rt < 2; rt++) {
        int r = row_base + rt * 16 + n16;
        if (r > NN - 1) r = NN - 1;
        const unsigned char* ap = A8 + (size_t)r * 128 + quad * 8;
#pragma unroll
        for (int ks = 0; ks < 4; ks++)
            a[rt][ks] = *(const uint2*)(ap + ks * 32);
    }

    f32x4 acc[2][8];
#pragma unroll
    for (int rt = 0; rt < 2; rt++)
#pragma unroll
        for (int ct = 0; ct < 8; ct++)
            acc[rt][ct] = (f32x4){0.f, 0.f, 0.f, 0.f};

#pragma unroll
    for (int ks = 0; ks < 4; ks++) {
        long a0 = __builtin_bit_cast(long, a[0][ks]);
        long a1 = __builtin_bit_cast(long, a[1][ks]);
#pragma unroll
        for (int ct = 0; ct < 8; ct++) {
            uint2 bv = *(const uint2*)(Ws + (ct * 16 + n16) * 128 +
                                       ((((ks << 2) + quad) ^ n16) << 3));
            long bb = __builtin_bit_cast(long, bv);
            acc[0][ct] = __builtin_amdgcn_mfma_f32_16x16x32_fp8_fp8(a0, bb, acc[0][ct], 0, 0, 0);
            acc[1][ct] = __builtin_amdgcn_mfma_f32_16x16x32_fp8_fp8(a1, bb, acc[1][ct], 0, 0, 0);
        }
    }

#pragma unroll
    for (int rt = 0; rt < 2; rt++) {
#pragma unroll
        for (int reg = 0; reg < 4; reg++) {
            int row = row_base + rt * 16 + quad * 4 + reg;
            if (row < NN) {
                float di = dinv[row];
                unsigned int u0 = 0, u1 = 0;
                u0 = f2f8_lo(acc[rt][0][reg] * di, acc[rt][1][reg] * di, u0);
                u0 = f2f8_hi(acc[rt][2][reg] * di, acc[rt][3][reg] * di, u0);
                u1 = f2f8_lo(acc[rt][4][reg] * di, acc[rt][5][reg] * di, u1);
                u1 = f2f8_hi(acc[rt][6][reg] * di, acc[rt][7][reg] * di, u1);
                uint2 o; o.x = u0; o.y = u1;
                ((uint2*)(Hs8 + (size_t)row * 128))[n16] = o;
            }
        }
    }
}

// ---------------------------------------------------------------- aggregation
// out[i] = relu( dinv[i] * (Hs[i] + sum_e Hs[src_e]) + bias ), fp8 permuted out.
// Sub-owns-node, deep-pipelined, DEGREE-SORTED: nodes come via perm[] ordered
// by descending padded degree, so the 4 subs of a wave have near-equal trip
// counts (no masked iterations) and the upper-8 branch is wave-uniform.
__global__ __launch_bounds__(256) void k_agg(const unsigned char* __restrict__ Hb,
                                             const unsigned int* __restrict__ meta,
                                             const int* __restrict__ csr_src,
                                             const float* __restrict__ dinv,
                                             const float* __restrict__ biasp,
                                             const int* __restrict__ perm,
                                             unsigned char* __restrict__ outp) {
    int node = perm[blockIdx.x * 16 + (threadIdx.x >> 4)];
    int li = threadIdx.x & 15;
    unsigned lo8 = (unsigned)li * 8u;
    unsigned int md = meta[node];
    int base = (int)(md & 0x3FFFFFu);
    int degp = (int)(md >> 22);
    f32x2 A0 = {0.f, 0.f}, A1 = {0.f, 0.f}, A2 = {0.f, 0.f}, A3 = {0.f, 0.f};
#define LDH(idx) (*(const uint2*)(Hb + (unsigned)(idx) * 128u + lo8))
#define ACC8(V) { \
        A0 += f8_2f<0>((V).x); A1 += f8_2f<1>((V).x); \
        A2 += f8_2f<0>((V).y); A3 += f8_2f<1>((V).y); }
    uint2 v = LDH(node);  // self (already dinv-scaled)
    const int4* ip = (const int4*)(csr_src + base);
    int4 i0 = ip[0], i1 = ip[1], i2 = ip[2], i3 = ip[3];  // slack-safe overread
    ACC8(v)
    for (int e0 = 0; e0 < degp; e0 += 16) {
        // lower 8: always within padded segment (degp is a multiple of 8)
        uint2 w0 = LDH(i0.x), w1 = LDH(i0.y), w2 = LDH(i0.z), w3 = LDH(i0.w);
        uint2 w4 = LDH(i1.x), w5 = LDH(i1.y), w6 = LDH(i1.z), w7 = LDH(i1.w);
        uint2 w8 = {0, 0}, w9 = {0, 0}, wA = {0, 0}, wB = {0, 0};
        uint2 wC = {0, 0}, wD = {0, 0}, wE = {0, 0}, wF = {0, 0};
        if (e0 + 8 < degp) {  // wave-uniform under degree sort
            w8 = LDH(i2.x); w9 = LDH(i2.y); wA = LDH(i2.z); wB = LDH(i2.w);
            wC = LDH(i3.x); wD = LDH(i3.y); wE = LDH(i3.z); wF = LDH(i3.w);
        }
        if (e0 + 16 < degp) {  // prefetch next index batch during accumulate
            const int4* np = (const int4*)(csr_src + base + e0 + 16);
            i0 = np[0]; i1 = np[1]; i2 = np[2]; i3 = np[3];
        }
        ACC8(w0) ACC8(w1) ACC8(w2) ACC8(w3)
        ACC8(w4) ACC8(w5) ACC8(w6) ACC8(w7)
        ACC8(w8) ACC8(w9) ACC8(wA) ACC8(wB)
        ACC8(wC) ACC8(wD) ACC8(wE) ACC8(wF)
    }
#undef ACC8
#undef LDH
    float di = dinv[node];
    const float4* b4 = (const float4*)biasp;  // permuted bias
    float4 bA = b4[li * 2], bB = b4[li * 2 + 1];
    float r0 = fmaxf(fmaf(di, A0[0], bA.x), 0.f);
    float r1 = fmaxf(fmaf(di, A0[1], bA.y), 0.f);
    float r2 = fmaxf(fmaf(di, A1[0], bA.z), 0.f);
    float r3 = fmaxf(fmaf(di, A1[1], bA.w), 0.f);
    float r4 = fmaxf(fmaf(di, A2[0], bB.x), 0.f);
    float r5 = fmaxf(fmaf(di, A2[1], bB.y), 0.f);
    float r6 = fmaxf(fmaf(di, A3[0], bB.z), 0.f);
    float r7 = fmaxf(fmaf(di, A3[1], bB.w), 0.f);
    unsigned int u0 = 0, u1 = 0;
    u0 = f2f8_lo(r0, r1, u0); u0 = f2f8_hi(r2, r3, u0);
    u1 = f2f8_lo(r4, r5, u1); u1 = f2f8_hi(r6, r7, u1);
    uint2 o; o.x = u0; o.y = u1;
    *(uint2*)(outp + (unsigned)node * 128u + lo8) = o;
}

// ------------------------------------------------- fused mean-pool + head MLP
// A2: fp8 permuted. part[] indexed by permuted byte q; hc[] unpermutes.
// Graph ranges come precomputed from k_prep's gstart scan (no binary search).
__global__ __launch_bounds__(256) void k_poolhead(const unsigned char* __restrict__ A,
                                                  const int* __restrict__ gstart,
                                                  const float* __restrict__ u,
                                                  const float* __restrict__ Wh1,
                                                  const float* __restrict__ bh1,
                                                  const float* __restrict__ Wh2,
                                                  const float* __restrict__ bh2,
                                                  float* __restrict__ out) {
    int g = blockIdx.x, t = threadIdx.x;
    int start = gstart[g];
    int end = gstart[g + 1];

    int li = t & 7;    // 16-byte chunk of the 128B row
    int ri = t >> 3;   // row offset 0..31
    float acc[16];
#pragma unroll
    for (int j = 0; j < 16; j++) acc[j] = 0.f;
    f32x2 p;
    for (int i = start + ri; i < end; i += 32) {
        uint4 v = ((const uint4*)A)[(size_t)i * 8 + li];
#define UP(VV, base) p = f8_2f<0>(VV); acc[base] += p.x; acc[base+1] += p.y; \
                     p = f8_2f<1>(VV); acc[base+2] += p.x; acc[base+3] += p.y;
        UP(v.x, 0) UP(v.y, 4) UP(v.z, 8) UP(v.w, 12)
#undef UP
    }
#pragma unroll
    for (int j = 0; j < 16; j++) {
        acc[j] += __shfl_xor(acc[j], 8);
        acc[j] += __shfl_xor(acc[j], 16);
        acc[j] += __shfl_xor(acc[j], 32);
    }
    __shared__ float part[4][128];
    __shared__ float hc[192];
    __shared__ float tt[128];
    __shared__ float red[8];
    int w = t >> 6;
    if ((t & 63) < 8) {
#pragma unroll
        for (int j = 0; j < 16; j++) part[w][li * 16 + j] = acc[j];  // index = byte q
    }
    __syncthreads();
    float cntf = (float)max(end - start, 1);
    if (t < 128) {
        int q = (t & 15) * 8 + (t >> 4);  // permuted position of col t
        hc[t] = (part[0][q] + part[1][q] + part[2][q] + part[3][q]) / cntf;
    } else if (t < 192) {
        hc[t] = u[g * 64 + (t - 128)];
    }
    __syncthreads();
    if (t < 128) {
        float a2 = bh1[t];
#pragma unroll 8
        for (int k = 0; k < 192; k++) a2 = fmaf(hc[k], Wh1[k * 128 + t], a2);
        tt[t] = fmaxf(a2, 0.f);
    }
    __syncthreads();
    // final 128->2 layer: parallel products + shuffle-tree reduce
    float p0 = 0.f, p1 = 0.f;
    if (t < 128) {
        float vv = tt[t];
        p0 = vv * Wh2[t * 2];
        p1 = vv * Wh2[t * 2 + 1];
    }
#pragma unroll
    for (int d = 32; d >= 1; d >>= 1) {
        p0 += __shfl_xor(p0, d);
        p1 += __shfl_xor(p1, d);
    }
    if ((t & 63) == 0) { red[w * 2] = p0; red[w * 2 + 1] = p1; }
    __syncthreads();
    if (t == 0) out[g * 2 + 0] = bh2[0] + red[0] + red[2];
    if (t == 1) out[g * 2 + 1] = bh2[1] + red[1] + red[3];
}

// ---------------------------------------------------------------- launcher
extern "C" void kernel_launch(void* const* d_in, const int* in_sizes, int n_in,
                              void* d_out, int out_size, void* d_ws, size_t ws_size,
                              hipStream_t stream) {
    const float* x   = (const float*)d_in[0];
    const int*   ei  = (const int*)d_in[1];
    const int*   row = ei;        // edge_index[0] = src
    const int*   col = ei + NE;   // edge_index[1] = dst
    const float* u   = (const float*)d_in[2];
    const int*   batch = (const int*)d_in[3];
    const float* W1  = (const float*)d_in[5];
    const float* b1  = (const float*)d_in[6];
    const float* W2  = (const float*)d_in[7];
    const float* b2  = (const float*)d_in[8];
    const float* Wh1 = (const float*)d_in[9];
    const float* bh1 = (const float*)d_in[10];
    const float* Wh2 = (const float*)d_in[11];
    const float* bh2 = (const float*)d_in[12];
    float* out = (float*)d_out;

    char* ws = (char*)d_ws;
    size_t o = 0;
    auto alloc = [&](size_t bytes) -> void* {
        void* p = ws + o;
        o += (bytes + 511) & ~(size_t)511;
        return p;
    };
    unsigned char*  Hs8 = (unsigned char*)alloc((size_t)(NN + 1) * 128); // +dummy zero row
    unsigned char*  A1b = (unsigned char*)alloc((size_t)NN * 128);   // fp8 permuted
    unsigned char*  A2b = (unsigned char*)alloc((size_t)NN * 128);   // fp8 permuted
    unsigned short* Wt1 = (unsigned short*)alloc((size_t)128 * 128 * 2);
    unsigned char*  Wt2p= (unsigned char*)alloc((size_t)128 * 128);
    float* b1p    = (float*)alloc((size_t)128 * 4);
    float* b2p    = (float*)alloc((size_t)128 * 4);
    float* dinv   = (float*)alloc((size_t)NN * 4);
    unsigned int* meta = (unsigned int*)alloc((size_t)NN * 4);
    int*   csr_src= (int*)alloc((size_t)NBK * SLOTC * 4 + 512);  // +slack for overread
    unsigned int* tmp = (unsigned int*)alloc((size_t)NBK * SLOT * 4);
    int*   gcur   = (int*)alloc((size_t)256 * 4);
    int*   gstart = (int*)alloc((size_t)(NG + 1) * 4);
    int*   dbins  = (int*)alloc((size_t)64 * 4);
    int*   gbincur= (int*)alloc((size_t)64 * 4);
    int*   perm   = (int*)alloc((size_t)NN * 4);

    // --- prep (W transforms + cursors + biases + graph starts) & CSR build ---
    k_prep<<<129 + cdiv(NN + 1, 256), 256, 0, stream>>>(W1, W2, b1, b2, Wt1, Wt2p,
                                                        b1p, b2p, gcur, batch, gstart,
                                                        Hs8, dbins);
    k_bin2<<<400, 256, 0, stream>>>(row, col, gcur, tmp);
    k_bucket<<<NBK, 1024, 0, stream>>>(tmp, gcur, meta, dinv, csr_src, dbins);
    k_scan<<<1, 64, 0, stream>>>(dbins, gbincur);
    k_scatter<<<cdiv(NN, 256), 256, 0, stream>>>(meta, gbincur, perm);

    // --- layer 1 (f32 input, bf16 MFMA; fp8 H) ---
    k_gemm1<<<cdiv(NN, 128), 256, 0, stream>>>(x, Wt1, dinv, Hs8);
    k_agg<<<NN / 16, 256, 0, stream>>>(Hs8, meta, csr_src, dinv, b1p, perm, A1b);
    // --- layer 2 (fp8 input, fp8 MFMA) ---
    k_gemm2<<<cdiv(NN, 128), 256, 0, stream>>>(A1b, Wt2p, dinv, Hs8);
    k_agg<<<NN / 16, 256, 0, stream>>>(Hs8, meta, csr_src, dinv, b2p, perm, A2b);

    // --- fused mean pool + head ---
    k_poolhead<<<NG, 256, 0, stream>>>(A2b, gstart, u, Wh1, bh1, Wh2, bh2, out);
}

// Round 4
// 232.558 us; speedup vs baseline: 1.0569x; 1.0569x over previous
//
#include <hip/hip_runtime.h>
#include <hip/hip_bf16.h>

#define NN 100000   // nodes
#define NE 1600000  // edges
#define NG 1000     // graphs
#define NBK 196     // dst buckets of 512 nodes (196*512 >= NN)
#define BSH 9       // bucket shift
#define SLOT 10240  // tmp slack region per bucket (mean 8192 + padding)
#define SLOTC 12288 // csr slack region per bucket (mean 8192 + 8-align pad ~3.5/node)

typedef short short8 __attribute__((ext_vector_type(8)));
typedef float f32x4 __attribute__((ext_vector_type(4)));
typedef float f32x2 __attribute__((ext_vector_type(2)));

static inline int cdiv(int a, int b) { return (a + b - 1) / b; }

// f32 -> bf16 (RNE) and helpers
__device__ __forceinline__ unsigned short f2b(float f) {
    unsigned int u = __float_as_uint(f);
    u += 0x7fff + ((u >> 16) & 1);
    return (unsigned short)(u >> 16);
}
__device__ __forceinline__ unsigned int pack2(float lo, float hi) {
    return (unsigned int)f2b(lo) | ((unsigned int)f2b(hi) << 16);
}

// fp8 e4m3 (OCP) hardware converts; word select must be an immediate constant
template <int W>
__device__ __forceinline__ f32x2 f8_2f(unsigned int v) {
    return __builtin_amdgcn_cvt_pk_f32_fp8((int)v, W);
}
__device__ __forceinline__ unsigned int f2f8_lo(float a, float b, unsigned int old) {
    return (unsigned int)__builtin_amdgcn_cvt_pk_fp8_f32(a, b, (int)old, false);
}
__device__ __forceinline__ unsigned int f2f8_hi(float a, float b, unsigned int old) {
    return (unsigned int)__builtin_amdgcn_cvt_pk_fp8_f32(a, b, (int)old, true);
}
__device__ __forceinline__ unsigned char f2f8s(float a) {
    return (unsigned char)(__builtin_amdgcn_cvt_pk_fp8_f32(a, a, 0, false) & 0xFF);
}

// ------------------------------------------------- prep
// Permuted byte order for fp8 rows: byte q holds col c(q) = (q&7)*16 + (q>>3).
// Wt1: bf16 [n][k] for layer-1 bf16 MFMA.
// Wt2p: fp8 [n][q] with k-rows permuted by the SAME c(q) as A1's byte order —
// joint k-permutation of A and B leaves the dot product invariant.
// Block 128 also zeroes row NN of BOTH gather buffers (dummy pad target).
// Blocks >= 129: scan sorted batch[] for graph start offsets.
__global__ __launch_bounds__(256) void k_prep(const float* __restrict__ W1,
                                              const float* __restrict__ W2,
                                              const float* __restrict__ b1,
                                              const float* __restrict__ b2,
                                              unsigned short* __restrict__ Wt1,
                                              unsigned char* __restrict__ Wt2p,
                                              float* __restrict__ b1p,
                                              float* __restrict__ b2p,
                                              int* __restrict__ gcur,
                                              const int* __restrict__ batch,
                                              int* __restrict__ gstart,
                                              unsigned char* __restrict__ Hs8,
                                              unsigned char* __restrict__ Hg2) {
    int b = blockIdx.x, t = threadIdx.x;
    if (b < 128) {
        if (t < 128) {
            Wt1[b * 128 + t] = f2b(W1[t * 128 + b]);
        } else {
            int q = t - 128;
            int c = (q & 7) * 16 + (q >> 3);
            Wt2p[b * 128 + q] = f2f8s(W2[c * 128 + b]);
        }
    } else if (b == 128) {
        if (t < NBK) gcur[t] = t * SLOT;
        if (t < 128) {
            int c = (t & 7) * 16 + (t >> 3);  // col held at permuted position t
            b1p[t] = b1[c];
            b2p[t] = b2[c];
        }
        if (t >= 128 && t < 136) {
            uint4 z; z.x = 0u; z.y = 0u; z.z = 0u; z.w = 0u;
            ((uint4*)(Hs8 + (size_t)NN * 128))[t - 128] = z;  // zero dummy row L1
        }
        if (t >= 136 && t < 144) {
            uint4 z; z.x = 0u; z.y = 0u; z.z = 0u; z.w = 0u;
            ((uint4*)(Hg2 + (size_t)NN * 128))[t - 136] = z;  // zero dummy row L2
        }
    } else {
        // graph boundary scan: n in [0, NN]; virtual batch[NN] = NG
        int n = (b - 129) * 256 + t;
        if (n <= NN) {
            int cur = (n == NN) ? NG : batch[n];
            int prev = (n == 0) ? -1 : batch[n - 1];
            for (int g = prev + 1; g <= cur; g++) gstart[g] = n;
        }
    }
}

// -------------------------------------------------------- two-phase binning
// LDS counting-sort (R17-verified): entries sorted into bucket order in LDS,
// then written out linearly (coalesced).
__global__ __launch_bounds__(256) void k_bin2(const int* __restrict__ row,
                                              const int* __restrict__ col,
                                              int* __restrict__ gcur,
                                              unsigned int* __restrict__ tmp) {
    __shared__ unsigned int ent[4000];
    __shared__ unsigned int srt[4000];
    __shared__ unsigned char bkt[4000];
    __shared__ unsigned char bky[4000];
    __shared__ int cnt[NBK];
    __shared__ int gbase[NBK];
    __shared__ int lbase[NBK];
    __shared__ int sh[256];
    int t = threadIdx.x;
    if (t < NBK) cnt[t] = 0;
    __syncthreads();
    const int q0 = blockIdx.x * 1000;  // int4 index base (4000 edges)
    const int4* col4 = (const int4*)col;
    const int4* row4 = (const int4*)row;
#pragma unroll
    for (int it = 0; it < 4; it++) {
        int idx = it * 256 + t;
        if (idx < 1000) {
            int4 c = col4[q0 + idx];
            int4 r = row4[q0 + idx];
            int d, b;
            d = c.x; b = d >> BSH; atomicAdd(&cnt[b], 1);
            ent[idx * 4 + 0] = ((unsigned int)(d & 511) << 17) | (unsigned int)r.x;
            bkt[idx * 4 + 0] = (unsigned char)b;
            d = c.y; b = d >> BSH; atomicAdd(&cnt[b], 1);
            ent[idx * 4 + 1] = ((unsigned int)(d & 511) << 17) | (unsigned int)r.y;
            bkt[idx * 4 + 1] = (unsigned char)b;
            d = c.z; b = d >> BSH; atomicAdd(&cnt[b], 1);
            ent[idx * 4 + 2] = ((unsigned int)(d & 511) << 17) | (unsigned int)r.z;
            bkt[idx * 4 + 2] = (unsigned char)b;
            d = c.w; b = d >> BSH; atomicAdd(&cnt[b], 1);
            ent[idx * 4 + 3] = ((unsigned int)(d & 511) << 17) | (unsigned int)r.w;
            bkt[idx * 4 + 3] = (unsigned char)b;
        }
    }
    __syncthreads();
    int v = (t < NBK) ? cnt[t] : 0;
    sh[t] = v;
    __syncthreads();
    for (int d = 1; d < 256; d <<= 1) {
        int u = (t >= d) ? sh[t - d] : 0;
        __syncthreads();
        sh[t] += u;
        __syncthreads();
    }
    if (t < NBK) {
        lbase[t] = sh[t] - v;
        gbase[t] = atomicAdd(&gcur[t], v);
        cnt[t] = sh[t] - v;  // becomes local cursor
    }
    __syncthreads();
#pragma unroll
    for (int it = 0; it < 16; it++) {
        int i = it * 256 + t;
        if (i < 4000) {
            int b = bkt[i];
            int p = atomicAdd(&cnt[b], 1);
            srt[p] = ent[i];
            bky[p] = (unsigned char)b;
        }
    }
    __syncthreads();
#pragma unroll
    for (int it = 0; it < 16; it++) {
        int i = it * 256 + t;
        if (i < 4000) {
            int b = bky[i];
            tmp[gbase[b] + (i - lbase[b])] = srt[i];
        }
    }
}

// -------------------------------------------------------- per-bucket CSR
// Segments padded to 8-entry alignment; pad entries filled with dummy index NN
// (points at the zeroed row of the gather buffer) so k_agg gathers
// unconditionally. meta[node] = csr_offset | (padded_degree << 22).
// Entries stashed in LDS during the count pass (no tmp re-read).
__global__ __launch_bounds__(1024) void k_bucket(const unsigned int* __restrict__ tmp,
                                                 const int* __restrict__ gcur,
                                                 unsigned int* __restrict__ meta,
                                                 float* __restrict__ dinv,
                                                 int* __restrict__ csr_src) {
    __shared__ unsigned int sent[SLOT];  // 40 KB entry stash
    __shared__ int cnt[512];
    __shared__ int loff[512];
    __shared__ int send[512];
    __shared__ int sh[256];
    int b = blockIdx.x, t = threadIdx.x;
    int j0 = b << BSH;
    int nd = min(512, NN - j0);
    int rb = b * SLOT;     // tmp base
    int rbc = b * SLOTC;   // csr base
    int m = gcur[b] - rb;
    if (t < 512) cnt[t] = 0;
    __syncthreads();
    for (int i = t; i < m; i += 1024) {
        unsigned int e = tmp[rb + i];
        sent[i] = e;
        atomicAdd(&cnt[e >> 17], 1);
    }
    __syncthreads();
    int r0 = 0, r1 = 0, p0 = 0, ts = 0;
    if (t < 256) {
        r0 = cnt[2 * t]; r1 = cnt[2 * t + 1];
        p0 = (r0 + 7) & ~7;
        int p1 = (r1 + 7) & ~7;  // pad to 8-entry alignment
        ts = p0 + p1;
        sh[t] = ts;
    }
    __syncthreads();
    for (int d = 1; d < 256; d <<= 1) {
        int u = (t >= d && t < 256) ? sh[t - d] : 0;
        __syncthreads();
        if (t < 256) sh[t] += u;
        __syncthreads();
    }
    if (t < 256) {
        int ex = sh[t] - ts;
        loff[2 * t] = ex;
        loff[2 * t + 1] = ex + p0;
    }
    __syncthreads();
    for (int j = t; j < nd; j += 1024) {
        int o = rbc + loff[j];
        int dg = cnt[j];
        int dgp = (dg + 7) & ~7;
        meta[j0 + j] = (unsigned int)o | ((unsigned int)dgp << 22);
        send[j] = o + dgp;
        dinv[j0 + j] = rsqrtf((float)(dg + 1));  // +1 self-loop
        cnt[j] = o;  // becomes cursor
    }
    __syncthreads();
    for (int i = t; i < m; i += 1024) {
        unsigned int e = sent[i];
        int d = e >> 17;
        int s = (int)(e & 0x1FFFFu);
        int p = atomicAdd(&cnt[d], 1);
        csr_src[p] = s;
    }
    __syncthreads();
    for (int j = t; j < nd; j += 1024) {
        int pe = send[j];
        for (int p = cnt[j]; p < pe; p++) csr_src[p] = NN;  // dummy (zero row)
    }
}

// ---------------------------------------------------------------- GEMM layer 1
// Hs8[r] = fp8( dinv[r] * (bf16(x) @ Wt1^T) row r ), PERMUTED bytes (q=n16*8+ct).
__global__ __launch_bounds__(256) void k_gemm1(const float* __restrict__ X,
                                               const unsigned short* __restrict__ Wt,
                                               const float* __restrict__ dinv,
                                               unsigned char* __restrict__ Hs8) {
    __shared__ __align__(16) unsigned short Ws[128 * 128];  // 32 KB
    int t = threadIdx.x;
#pragma unroll
    for (int i = 0; i < 8; i++) {
        int id = t + i * 256;
        int n = id >> 4, c = id & 15;
        *(short8*)((char*)Ws + n * 256 + ((c ^ (n & 15)) << 4)) =
            *(const short8*)(Wt + n * 128 + c * 8);
    }
    __syncthreads();

    int lane = t & 63, wid = t >> 6;
    int n16 = lane & 15, quad = lane >> 4;
    int row_base = blockIdx.x * 128 + wid * 32;

    short8 a[2][4];
#pragma unroll
    for (int rt = 0; rt < 2; rt++) {
        int r = row_base + rt * 16 + n16;
        if (r > NN - 1) r = NN - 1;
        const float* ap = X + (size_t)r * 128 + quad * 8;
#pragma unroll
        for (int ks = 0; ks < 4; ks++) {
            float4 v0 = *(const float4*)(ap + ks * 32);
            float4 v1 = *(const float4*)(ap + ks * 32 + 4);
            uint4 up;
            up.x = pack2(v0.x, v0.y); up.y = pack2(v0.z, v0.w);
            up.z = pack2(v1.x, v1.y); up.w = pack2(v1.z, v1.w);
            a[rt][ks] = *(short8*)&up;
        }
    }

    f32x4 acc[2][8];
#pragma unroll
    for (int rt = 0; rt < 2; rt++)
#pragma unroll
        for (int ct = 0; ct < 8; ct++)
            acc[rt][ct] = (f32x4){0.f, 0.f, 0.f, 0.f};

#pragma unroll
    for (int ks = 0; ks < 4; ks++) {
#pragma unroll
        for (int ct = 0; ct < 8; ct++) {
            short8 b = *(const short8*)((const char*)Ws +
                        (ct * 16 + n16) * 256 + ((((ks << 2) + quad) ^ n16) << 4));
            acc[0][ct] = __builtin_amdgcn_mfma_f32_16x16x32_bf16(a[0][ks], b, acc[0][ct], 0, 0, 0);
            acc[1][ct] = __builtin_amdgcn_mfma_f32_16x16x32_bf16(a[1][ks], b, acc[1][ct], 0, 0, 0);
        }
    }

#pragma unroll
    for (int rt = 0; rt < 2; rt++) {
#pragma unroll
        for (int reg = 0; reg < 4; reg++) {
            int row = row_base + rt * 16 + quad * 4 + reg;
            if (row < NN) {
                float di = dinv[row];
                unsigned int u0 = 0, u1 = 0;
                u0 = f2f8_lo(acc[rt][0][reg] * di, acc[rt][1][reg] * di, u0);
                u0 = f2f8_hi(acc[rt][2][reg] * di, acc[rt][3][reg] * di, u0);
                u1 = f2f8_lo(acc[rt][4][reg] * di, acc[rt][5][reg] * di, u1);
                u1 = f2f8_hi(acc[rt][6][reg] * di, acc[rt][7][reg] * di, u1);
                uint2 o; o.x = u0; o.y = u1;
                ((uint2*)(Hs8 + (size_t)row * 128))[n16] = o;
            }
        }
    }
}

// ------------------------------------------- aggregation (+fused layer-2 GEMM)
// out[i] = relu( dinv[i] * (Hs[i] + sum_e Hs[src_e]) + bias ), fp8 permuted.
// Sub-owns-node, deep-pipelined: 16 edges/iter, 16 gathers in flight, index
// prefetch. CSR 8-padded with dummy index NN (zero row) -> lower 8 gathers
// unconditional.
// FUSE=1: instead of storing the relu'd A1 row, stage it in a 16x128 fp8 LDS
// tile (XOR-chunk swizzle), stage W2 (fp8, k-permuted) in 16 KB LDS, then
// wave 0 computes the 16x128 @ 128x128 fp8 MFMA product and writes
// dinv-scaled fp8 rows (identical math to the standalone k_gemm2).
template <int FUSE>
__global__ __launch_bounds__(256) void k_agg(const unsigned char* __restrict__ Hb,
                                             const unsigned int* __restrict__ meta,
                                             const int* __restrict__ csr_src,
                                             const float* __restrict__ dinv,
                                             const float* __restrict__ biasp,
                                             const unsigned char* __restrict__ Wt2p,
                                             unsigned char* __restrict__ outp) {
    __shared__ __align__(16) unsigned char sm[FUSE ? (128 * 128 + 16 * 128) : 16];
    int t = threadIdx.x;
    if (FUSE) {  // stage W2 into LDS (same swizzle as standalone gemm2)
#pragma unroll
        for (int i = 0; i < 8; i++) {
            int id = t + i * 256;          // 2048 8-byte chunks
            int n = id >> 4, c = id & 15;
            *(uint2*)(sm + n * 128 + ((c ^ (n & 15)) << 3)) =
                *(const uint2*)(Wt2p + n * 128 + c * 8);
        }
    }
    int sub = t >> 4;
    int node = blockIdx.x * 16 + sub;
    int li = t & 15;
    unsigned lo8 = (unsigned)li * 8u;
    unsigned int md = meta[node];
    int base = (int)(md & 0x3FFFFFu);
    int degp = (int)(md >> 22);
    f32x2 A0 = {0.f, 0.f}, A1 = {0.f, 0.f}, A2 = {0.f, 0.f}, A3 = {0.f, 0.f};
#define LDH(idx) (*(const uint2*)(Hb + (unsigned)(idx) * 128u + lo8))
#define ACC8(V) { \
        A0 += f8_2f<0>((V).x); A1 += f8_2f<1>((V).x); \
        A2 += f8_2f<0>((V).y); A3 += f8_2f<1>((V).y); }
    uint2 v = LDH(node);  // self (already dinv-scaled)
    const int4* ip = (const int4*)(csr_src + base);
    int4 i0 = ip[0], i1 = ip[1], i2 = ip[2], i3 = ip[3];  // slack-safe overread
    ACC8(v)
    for (int e0 = 0; e0 < degp; e0 += 16) {
        // lower 8: always within padded segment (degp is a multiple of 8)
        uint2 w0 = LDH(i0.x), w1 = LDH(i0.y), w2 = LDH(i0.z), w3 = LDH(i0.w);
        uint2 w4 = LDH(i1.x), w5 = LDH(i1.y), w6 = LDH(i1.z), w7 = LDH(i1.w);
        uint2 w8 = {0, 0}, w9 = {0, 0}, wA = {0, 0}, wB = {0, 0};
        uint2 wC = {0, 0}, wD = {0, 0}, wE = {0, 0}, wF = {0, 0};
        if (e0 + 8 < degp) {  // sub-uniform
            w8 = LDH(i2.x); w9 = LDH(i2.y); wA = LDH(i2.z); wB = LDH(i2.w);
            wC = LDH(i3.x); wD = LDH(i3.y); wE = LDH(i3.z); wF = LDH(i3.w);
        }
        if (e0 + 16 < degp) {  // prefetch next index batch during accumulate
            const int4* np = (const int4*)(csr_src + base + e0 + 16);
            i0 = np[0]; i1 = np[1]; i2 = np[2]; i3 = np[3];
        }
        ACC8(w0) ACC8(w1) ACC8(w2) ACC8(w3)
        ACC8(w4) ACC8(w5) ACC8(w6) ACC8(w7)
        ACC8(w8) ACC8(w9) ACC8(wA) ACC8(wB)
        ACC8(wC) ACC8(wD) ACC8(wE) ACC8(wF)
    }
#undef ACC8
#undef LDH
    float di = dinv[node];
    const float4* b4 = (const float4*)biasp;  // permuted bias
    float4 bA = b4[li * 2], bB = b4[li * 2 + 1];
    float r0 = fmaxf(fmaf(di, A0[0], bA.x), 0.f);
    float r1 = fmaxf(fmaf(di, A0[1], bA.y), 0.f);
    float r2 = fmaxf(fmaf(di, A1[0], bA.z), 0.f);
    float r3 = fmaxf(fmaf(di, A1[1], bA.w), 0.f);
    float r4 = fmaxf(fmaf(di, A2[0], bB.x), 0.f);
    float r5 = fmaxf(fmaf(di, A2[1], bB.y), 0.f);
    float r6 = fmaxf(fmaf(di, A3[0], bB.z), 0.f);
    float r7 = fmaxf(fmaf(di, A3[1], bB.w), 0.f);
    unsigned int u0 = 0, u1 = 0;
    u0 = f2f8_lo(r0, r1, u0); u0 = f2f8_hi(r2, r3, u0);
    u1 = f2f8_lo(r4, r5, u1); u1 = f2f8_hi(r6, r7, u1);
    uint2 o; o.x = u0; o.y = u1;
    if (!FUSE) {
        *(uint2*)(outp + (unsigned)node * 128u + lo8) = o;
        return;
    }
    // ---- fused layer-2 GEMM path ----
    // A-tile: row = sub, 8B chunk li at XOR-swizzled slot (bijective per row)
    *(uint2*)(sm + 16384 + sub * 128 + (((li ^ sub) & 15) << 3)) = o;
    __syncthreads();
    if (t < 64) {
        int n16 = t & 15, quad = t >> 4;
        f32x4 acc[8];
#pragma unroll
        for (int ct = 0; ct < 8; ct++) acc[ct] = (f32x4){0.f, 0.f, 0.f, 0.f};
#pragma unroll
        for (int ks = 0; ks < 4; ks++) {
            uint2 av = *(const uint2*)(sm + 16384 + n16 * 128 +
                                       ((((ks << 2) + quad) ^ n16) << 3));
            long aa = __builtin_bit_cast(long, av);
#pragma unroll
            for (int ct = 0; ct < 8; ct++) {
                uint2 bv = *(const uint2*)(sm + (ct * 16 + n16) * 128 +
                                           ((((ks << 2) + quad) ^ n16) << 3));
                long bb = __builtin_bit_cast(long, bv);
                acc[ct] = __builtin_amdgcn_mfma_f32_16x16x32_fp8_fp8(aa, bb, acc[ct], 0, 0, 0);
            }
        }
#pragma unroll
        for (int reg = 0; reg < 4; reg++) {
            int row = blockIdx.x * 16 + quad * 4 + reg;
            float d2 = dinv[row];
            unsigned int g0 = 0, g1 = 0;
            g0 = f2f8_lo(acc[0][reg] * d2, acc[1][reg] * d2, g0);
            g0 = f2f8_hi(acc[2][reg] * d2, acc[3][reg] * d2, g0);
            g1 = f2f8_lo(acc[4][reg] * d2, acc[5][reg] * d2, g1);
            g1 = f2f8_hi(acc[6][reg] * d2, acc[7][reg] * d2, g1);
            uint2 go; go.x = g0; go.y = g1;
            ((uint2*)(outp + (size_t)row * 128))[n16] = go;
        }
    }
}

// ------------------------------------------------- fused mean-pool + head MLP
// A2: fp8 permuted. part[] indexed by permuted byte q; hc[] unpermutes.
// Graph ranges come precomputed from k_prep's gstart scan (no binary search).
__global__ __launch_bounds__(256) void k_poolhead(const unsigned char* __restrict__ A,
                                                  const int* __restrict__ gstart,
                                                  const float* __restrict__ u,
                                                  const float* __restrict__ Wh1,
                                                  const float* __restrict__ bh1,
                                                  const float* __restrict__ Wh2,
                                                  const float* __restrict__ bh2,
                                                  float* __restrict__ out) {
    int g = blockIdx.x, t = threadIdx.x;
    int start = gstart[g];
    int end = gstart[g + 1];

    int li = t & 7;    // 16-byte chunk of the 128B row
    int ri = t >> 3;   // row offset 0..31
    float acc[16];
#pragma unroll
    for (int j = 0; j < 16; j++) acc[j] = 0.f;
    f32x2 p;
    for (int i = start + ri; i < end; i += 32) {
        uint4 v = ((const uint4*)A)[(size_t)i * 8 + li];
#define UP(VV, base) p = f8_2f<0>(VV); acc[base] += p.x; acc[base+1] += p.y; \
                     p = f8_2f<1>(VV); acc[base+2] += p.x; acc[base+3] += p.y;
        UP(v.x, 0) UP(v.y, 4) UP(v.z, 8) UP(v.w, 12)
#undef UP
    }
#pragma unroll
    for (int j = 0; j < 16; j++) {
        acc[j] += __shfl_xor(acc[j], 8);
        acc[j] += __shfl_xor(acc[j], 16);
        acc[j] += __shfl_xor(acc[j], 32);
    }
    __shared__ float part[4][128];
    __shared__ float hc[192];
    __shared__ float tt[128];
    __shared__ float red[8];
    int w = t >> 6;
    if ((t & 63) < 8) {
#pragma unroll
        for (int j = 0; j < 16; j++) part[w][li * 16 + j] = acc[j];  // index = byte q
    }
    __syncthreads();
    float cntf = (float)max(end - start, 1);
    if (t < 128) {
        int q = (t & 15) * 8 + (t >> 4);  // permuted position of col t
        hc[t] = (part[0][q] + part[1][q] + part[2][q] + part[3][q]) / cntf;
    } else if (t < 192) {
        hc[t] = u[g * 64 + (t - 128)];
    }
    __syncthreads();
    if (t < 128) {
        float a2 = bh1[t];
#pragma unroll 8
        for (int k = 0; k < 192; k++) a2 = fmaf(hc[k], Wh1[k * 128 + t], a2);
        tt[t] = fmaxf(a2, 0.f);
    }
    __syncthreads();
    // final 128->2 layer: parallel products + shuffle-tree reduce
    float p0 = 0.f, p1 = 0.f;
    if (t < 128) {
        float vv = tt[t];
        p0 = vv * Wh2[t * 2];
        p1 = vv * Wh2[t * 2 + 1];
    }
#pragma unroll
    for (int d = 32; d >= 1; d >>= 1) {
        p0 += __shfl_xor(p0, d);
        p1 += __shfl_xor(p1, d);
    }
    if ((t & 63) == 0) { red[w * 2] = p0; red[w * 2 + 1] = p1; }
    __syncthreads();
    if (t == 0) out[g * 2 + 0] = bh2[0] + red[0] + red[2];
    if (t == 1) out[g * 2 + 1] = bh2[1] + red[1] + red[3];
}

// ---------------------------------------------------------------- launcher
extern "C" void kernel_launch(void* const* d_in, const int* in_sizes, int n_in,
                              void* d_out, int out_size, void* d_ws, size_t ws_size,
                              hipStream_t stream) {
    const float* x   = (const float*)d_in[0];
    const int*   ei  = (const int*)d_in[1];
    const int*   row = ei;        // edge_index[0] = src
    const int*   col = ei + NE;   // edge_index[1] = dst
    const float* u   = (const float*)d_in[2];
    const int*   batch = (const int*)d_in[3];
    const float* W1  = (const float*)d_in[5];
    const float* b1  = (const float*)d_in[6];
    const float* W2  = (const float*)d_in[7];
    const float* b2  = (const float*)d_in[8];
    const float* Wh1 = (const float*)d_in[9];
    const float* bh1 = (const float*)d_in[10];
    const float* Wh2 = (const float*)d_in[11];
    const float* bh2 = (const float*)d_in[12];
    float* out = (float*)d_out;

    char* ws = (char*)d_ws;
    size_t o = 0;
    auto alloc = [&](size_t bytes) -> void* {
        void* p = ws + o;
        o += (bytes + 511) & ~(size_t)511;
        return p;
    };
    unsigned char*  Hs8 = (unsigned char*)alloc((size_t)(NN + 1) * 128); // L1 pre-gather (+dummy)
    unsigned char*  Hg2 = (unsigned char*)alloc((size_t)(NN + 1) * 128); // L2 pre-gather (+dummy)
    unsigned char*  A2b = (unsigned char*)alloc((size_t)NN * 128);       // fp8 permuted
    unsigned short* Wt1 = (unsigned short*)alloc((size_t)128 * 128 * 2);
    unsigned char*  Wt2p= (unsigned char*)alloc((size_t)128 * 128);
    float* b1p    = (float*)alloc((size_t)128 * 4);
    float* b2p    = (float*)alloc((size_t)128 * 4);
    float* dinv   = (float*)alloc((size_t)NN * 4);
    unsigned int* meta = (unsigned int*)alloc((size_t)NN * 4);
    int*   csr_src= (int*)alloc((size_t)NBK * SLOTC * 4 + 512);  // +slack for overread
    unsigned int* tmp = (unsigned int*)alloc((size_t)NBK * SLOT * 4);
    int*   gcur   = (int*)alloc((size_t)256 * 4);
    int*   gstart = (int*)alloc((size_t)(NG + 1) * 4);

    // --- prep (W transforms + cursors + biases + graph starts) & CSR build ---
    k_prep<<<129 + cdiv(NN + 1, 256), 256, 0, stream>>>(W1, W2, b1, b2, Wt1, Wt2p,
                                                        b1p, b2p, gcur, batch, gstart,
                                                        Hs8, Hg2);
    k_bin2<<<400, 256, 0, stream>>>(row, col, gcur, tmp);
    k_bucket<<<NBK, 1024, 0, stream>>>(tmp, gcur, meta, dinv, csr_src);

    // --- layer 1 (f32 input, bf16 MFMA; fp8 H) ---
    k_gemm1<<<cdiv(NN, 128), 256, 0, stream>>>(x, Wt1, dinv, Hs8);
    // --- agg1 + layer-2 GEMM fused (writes L2 pre-gather buffer directly) ---
    k_agg<1><<<NN / 16, 256, 0, stream>>>(Hs8, meta, csr_src, dinv, b1p, Wt2p, Hg2);
    // --- agg2 (plain) ---
    k_agg<0><<<NN / 16, 256, 0, stream>>>(Hg2, meta, csr_src, dinv, b2p, nullptr, A2b);

    // --- fused mean pool + head ---
    k_poolhead<<<NG, 256, 0, stream>>>(A2b, gstart, u, Wh1, bh1, Wh2, bh2, out);
}